// Round 1
// baseline (969.757 us; speedup 1.0000x reference)
//
#include <hip/hip_runtime.h>
#include <cstdint>

typedef unsigned short u16;
typedef __attribute__((ext_vector_type(8))) u16 u16x8;
typedef __attribute__((ext_vector_type(4))) u16 u16x4;
typedef __attribute__((ext_vector_type(8))) __bf16 bf16x8;
typedef __attribute__((ext_vector_type(4))) float f32x4;

// ---------- helpers ----------
__device__ __forceinline__ u16 f2b(float f) {              // fp32 -> bf16 (RNE)
  unsigned u = __float_as_uint(f);
  u += 0x7fffu + ((u >> 16) & 1u);
  return (u16)(u >> 16);
}
__device__ __forceinline__ float b2f(u16 b) {
  return __uint_as_float(((unsigned)b) << 16);
}
// async global->LDS, 16B per lane. LDS dest = wave-uniform base + lane*16.
__device__ __forceinline__ void gll16(const void* g, void* l) {
  auto gp = reinterpret_cast<const __attribute__((address_space(1))) unsigned int*>(
      reinterpret_cast<uintptr_t>(g));
  auto lp = reinterpret_cast<__attribute__((address_space(3))) unsigned int*>(
      reinterpret_cast<uintptr_t>(l));
  __builtin_amdgcn_global_load_lds(gp, lp, 16, 0, 0);
}

// ---------- prep: NCHW fp32 -> padded(34x34) NHWC bf16 ----------
// grid = imgs*32 (block per (img,y)), block 256
__global__ __launch_bounds__(256) void pad_nhwc(const float* __restrict__ in,
                                                u16* __restrict__ outp) {
  const int img = blockIdx.x >> 5;
  const int y   = blockIdx.x & 31;
  __shared__ float tile[32][33];
  const int tid = threadIdx.x;
  const int xi = tid & 31, ci = tid >> 5;   // load role: 8c x 32x
  const int xo = tid >> 3, q = tid & 7;     // store role: 32x x 8 quads
  const float* ip = in + (long)img * 1048576 + y * 32;
  u16* op = outp + ((long)(img * 34) + y + 1) * 34 * 1024 + 1024; // (y+1, x=1) base
  for (int c0 = 0; c0 < 1024; c0 += 32) {
#pragma unroll
    for (int k2 = 0; k2 < 4; k2++)
      tile[k2 * 8 + ci][xi] = ip[(long)(c0 + k2 * 8 + ci) * 1024 + xi];
    __syncthreads();
    u16x4 o4;
#pragma unroll
    for (int r = 0; r < 4; r++) o4[r] = f2b(tile[q * 4 + r][xo]);
    *(u16x4*)&op[(long)xo * 1024 + c0 + q * 4] = o4;
    __syncthreads();
  }
}

// ---------- prep: w[OC][1024][3][3] fp32 -> wT[OC][t*1024+c] bf16 ----------
__global__ __launch_bounds__(256) void wre3(const float* __restrict__ w,
                                            u16* __restrict__ o) {
  const int oc = blockIdx.x;
  __shared__ float buf[9216];
  const float* wp = w + (long)oc * 9216;
  for (int i = threadIdx.x; i < 9216; i += 256) buf[i] = wp[i];
  __syncthreads();
  u16* op = o + (long)oc * 9216;
  for (int k = threadIdx.x; k < 9216; k += 256) {
    int t = k >> 10, c = k & 1023;
    op[k] = f2b(buf[c * 9 + t]);
  }
}

__global__ __launch_bounds__(256) void cvt_lin(const float* __restrict__ in,
                                               u16* __restrict__ o, int n) {
  int i = (blockIdx.x * 256 + threadIdx.x) * 4;
  if (i + 3 < n) {
#pragma unroll
    for (int r = 0; r < 4; r++) o[i + r] = f2b(in[i + r]);
  }
}

// ---------- row softmax (in-place, bf16), grid = rows, block 256 ----------
__global__ __launch_bounds__(256) void row_softmax(u16* __restrict__ P, int L) {
  u16* p = P + (long)blockIdx.x * L;
  const int tid = threadIdx.x;
  const int nv = L >> 3;
  __shared__ float redmax[4], redsum[4];
  float mx = -3.0e38f;
  for (int i = tid; i < nv; i += 256) {
    u16x8 v = *(const u16x8*)(p + (i << 3));
#pragma unroll
    for (int j = 0; j < 8; j++) mx = fmaxf(mx, b2f(v[j]));
  }
#pragma unroll
  for (int o = 32; o > 0; o >>= 1) mx = fmaxf(mx, __shfl_xor(mx, o, 64));
  if ((tid & 63) == 0) redmax[tid >> 6] = mx;
  __syncthreads();
  mx = fmaxf(fmaxf(redmax[0], redmax[1]), fmaxf(redmax[2], redmax[3]));
  float s = 0.f;
  for (int i = tid; i < nv; i += 256) {
    u16x8 v = *(const u16x8*)(p + (i << 3));
#pragma unroll
    for (int j = 0; j < 8; j++) s += __expf(b2f(v[j]) - mx);
  }
#pragma unroll
  for (int o = 32; o > 0; o >>= 1) s += __shfl_xor(s, o, 64);
  if ((tid & 63) == 0) redsum[tid >> 6] = s;
  __syncthreads();
  s = redsum[0] + redsum[1] + redsum[2] + redsum[3];
  const float inv = 1.0f / s;
  for (int i = tid; i < nv; i += 256) {
    u16x8 v = *(const u16x8*)(p + (i << 3));
    u16x8 o8;
#pragma unroll
    for (int j = 0; j < 8; j++) o8[j] = f2b(__expf(b2f(v[j]) - mx) * inv);
    *(u16x8*)(p + (i << 3)) = o8;
  }
}

// ---------- unified NT GEMM: D[m][n] = sum_k A[m][k]*B[n][k] ----------
// BMODE: 0 = plain rows [n][K];  1 = 3x3 conv patches from padded NHWC;
//        2 = 1x1 conv (center) from padded NHWC
// EPI:   0 = bf16 transposed store out[n][ldo]+m (dual out at m>=128)
//        1 = bf16 row store out[z]+m*ldo+n, *scale (+bias)
//        2 = qf fp32: d_out[img][512+m][p]
//        3 = final fp32: d_out[z*5+f][m][p]
template <int BMODE, int EPI>
__global__ __launch_bounds__(256, 2)
void gemm_nt(const u16* __restrict__ A, long Azoff, int Astride,
             const u16* __restrict__ B, long Bzoff, int Bstride,
             int K, float scale,
             const float* __restrict__ bias, const float* __restrict__ bias2,
             void* __restrict__ out0, void* __restrict__ out1,
             long out_zoff, int ldo) {
  __shared__ u16 lds[4 * 8192];  // [buf][A(8192)|B(8192)]
  const int tid = threadIdx.x;
  const int lane = tid & 63;
  const int wave = tid >> 6;
  const int mtile = blockIdx.y, ntile = blockIdx.x, z = blockIdx.z;

  const u16* Ab = A + (long)z * Azoff;
  const u16* Bb = B + (long)z * Bzoff;

  // ---- staging setup (8 gll16 per wave per K-tile) ----
  const int r8 = lane >> 3;     // row within 8-row group
  const int sphys = lane & 7;   // physical 16B slot
  const u16* aSrc[4];
  const u16* bSrc[4];
  u16* aDst[4];
  u16* bDst[4];
#pragma unroll
  for (int i = 0; i < 4; i++) {
    const int row = wave * 32 + i * 8 + r8;
    const int slog = sphys ^ (row & 7);  // pre-swizzled source slot
    aSrc[i] = Ab + (long)(mtile * 128 + row) * Astride + slog * 8;
    if (BMODE == 0) {
      bSrc[i] = Bb + (long)(ntile * 128 + row) * Bstride + slog * 8;
    } else {
      const int n = ntile * 128 + row;
      const int img = n >> 10;
      const int p = n & 1023;
      const int y = p >> 5, x = p & 31;
      bSrc[i] = Bb + ((long)(img * 34 + y) * 34 + x) * 1024 + slog * 8;
    }
    aDst[i] = &lds[0] + (wave * 32 + i * 8) * 64;
    bDst[i] = &lds[0] + 8192 + (wave * 32 + i * 8) * 64;
  }

  // ---- loop-invariant fragment LDS offsets (swizzled reads) ----
  const int g = lane >> 4, l15 = lane & 15;
  const int wm = wave >> 1, wn = wave & 1;
  int offA[2][4], offB[2][4];
#pragma unroll
  for (int ks = 0; ks < 2; ks++) {
    const int sl = ks * 4 + g;
#pragma unroll
    for (int i = 0; i < 4; i++) {
      const int ra = wm * 64 + i * 16 + l15;
      offA[ks][i] = ra * 64 + ((sl ^ (ra & 7)) * 8);
      const int rb = wn * 64 + i * 16 + l15;
      offB[ks][i] = 8192 + rb * 64 + ((sl ^ (rb & 7)) * 8);
    }
  }

  auto stage = [&](int buf, int kb) {
    int bAdd;
    if (BMODE == 0) {
      bAdd = kb;
    } else if (BMODE == 1) {
      const int t = kb >> 10, c0 = kb & 1023;
      const int dy = t / 3, dx = t - dy * 3;
      bAdd = (dy * 34 + dx) * 1024 + c0;
    } else {
      bAdd = 35 * 1024 + kb;  // center tap (dy=dx=1)
    }
    const int bufo = buf * 16384;
#pragma unroll
    for (int i = 0; i < 4; i++) gll16(aSrc[i] + kb, aDst[i] + bufo);
#pragma unroll
    for (int i = 0; i < 4; i++) gll16(bSrc[i] + bAdd, bDst[i] + bufo);
  };

  f32x4 acc[4][4];
  const f32x4 zero = {0.f, 0.f, 0.f, 0.f};
#pragma unroll
  for (int i = 0; i < 4; i++)
#pragma unroll
    for (int j = 0; j < 4; j++) acc[i][j] = zero;

  const int nkt = K >> 6;
  stage(0, 0);
  __syncthreads();
  for (int kt = 0; kt < nkt; ++kt) {
    const int buf = kt & 1;
    if (kt + 1 < nkt) stage(buf ^ 1, (kt + 1) << 6);
#pragma unroll
    for (int ks = 0; ks < 2; ks++) {
      bf16x8 af[4], bfg[4];
#pragma unroll
      for (int i = 0; i < 4; i++)
        af[i] = *(const bf16x8*)&lds[buf * 16384 + offA[ks][i]];
#pragma unroll
      for (int i = 0; i < 4; i++)
        bfg[i] = *(const bf16x8*)&lds[buf * 16384 + offB[ks][i]];
#pragma unroll
      for (int mi = 0; mi < 4; mi++)
#pragma unroll
        for (int ni = 0; ni < 4; ni++)
          acc[mi][ni] = __builtin_amdgcn_mfma_f32_16x16x32_bf16(
              af[mi], bfg[ni], acc[mi][ni], 0, 0, 0);
    }
    __syncthreads();
  }

  // ---- epilogue ----
#pragma unroll
  for (int mi = 0; mi < 4; mi++) {
#pragma unroll
    for (int ni = 0; ni < 4; ni++) {
      f32x4 v = acc[mi][ni];
      const int m0 = mtile * 128 + wm * 64 + mi * 16 + g * 4;
      const int n = ntile * 128 + wn * 64 + ni * 16 + l15;
      if (EPI == 0) {
        u16* ob = (u16*)out0;
        const float* bs = bias;
        int mm = m0;
        if (out1 != nullptr && m0 >= 128) { ob = (u16*)out1; bs = bias2; mm = m0 - 128; }
        u16x4 pk;
#pragma unroll
        for (int r = 0; r < 4; r++) {
          float val = v[r] * scale + (bs ? bs[mm + r] : 0.f);
          pk[r] = f2b(val);
        }
        *(u16x4*)&ob[(long)n * ldo + mm] = pk;
      } else if (EPI == 1) {
        u16* ob = (u16*)out0 + (long)z * out_zoff;
#pragma unroll
        for (int r = 0; r < 4; r++) {
          const int m = m0 + r;
          float val = v[r] * scale + (bias ? bias[m] : 0.f);
          ob[(long)m * ldo + n] = f2b(val);
        }
      } else if (EPI == 2) {
        float* of = (float*)out0;
        const int img = n >> 10, p = n & 1023;
#pragma unroll
        for (int r = 0; r < 4; r++) {
          const int m = m0 + r;
          of[(long)img * 1048576 + (long)(512 + m) * 1024 + p] =
              v[r] + (bias ? bias[m] : 0.f);
        }
      } else {
        float* of = (float*)out0;
        const int f = n >> 10, p = n & 1023;
#pragma unroll
        for (int r = 0; r < 4; r++) {
          const int m = m0 + r;
          of[(long)z * 5242880 + (long)f * 1048576 + (long)m * 1024 + p] = v[r];
        }
      }
    }
  }
}

// ---------- launch ----------
extern "C" void kernel_launch(void* const* d_in, const int* in_sizes, int n_in,
                              void* d_out, int out_size, void* d_ws, size_t ws_size,
                              hipStream_t stream) {
  (void)in_sizes; (void)n_in; (void)out_size;
  const float* query   = (const float*)d_in[0];
  const float* support = (const float*)d_in[1];
  const float* w_sk = (const float*)d_in[2];  const float* b_sk = (const float*)d_in[3];
  const float* w_sv = (const float*)d_in[4];  const float* b_sv = (const float*)d_in[5];
  const float* w_qq = (const float*)d_in[6];  const float* b_qq = (const float*)d_in[7];
  const float* w_qk = (const float*)d_in[8];  const float* b_qk = (const float*)d_in[9];
  const float* w_cq = (const float*)d_in[10]; const float* b_cq = (const float*)d_in[11];
  float* out = (float*)d_out;
  char* ws = (char*)d_ws;

  if (ws_size < 158924800u) return;  // insufficient workspace

  u16* PQ    = (u16*)(ws + 0);           // padded query NHWC bf16: 10*34*34*1024
  u16* PS    = (u16*)(ws + 23674880);    // padded support: 30*34*34*1024
  u16* WTSK  = (u16*)(ws + 94699520);    // [128][9216]
  u16* WTSV  = (u16*)(ws + 97058816);    // [512][9216]
  u16* WTQQK = (u16*)(ws + 106496000);   // [256][9216] (qq rows 0-127, qk 128-255)
  u16* WCQ   = (u16*)(ws + 111214592);   // [512][1024]
  u16* SKR   = (u16*)(ws + 112263168);   // [30720][128]
  u16* SVA   = (u16*)(ws + 120127488);   // [2][512][15360]
  u16* QQR   = (u16*)(ws + 151584768);   // [10240][128]
  u16* QKR   = (u16*)(ws + 154206208);   // [10240][128]
  u16* NEWV  = (u16*)(ws + 156827648);   // [2][512][1024]
  u16* P1T   = PS;   // alias: [2][1024][15360] — after sk/sv convs consume PS
  u16* P2T   = PQ;   // alias: [2][5120][1024]  — after qqk/qf convs consume PQ

  const float SCALE = 0.08838834764831843f;  // 1/sqrt(128)

  hipMemsetAsync(PQ, 0, 23674880, stream);
  hipMemsetAsync(PS, 0, 71024640, stream);
  pad_nhwc<<<dim3(320), 256, 0, stream>>>(query, PQ);
  pad_nhwc<<<dim3(960), 256, 0, stream>>>(support, PS);
  wre3<<<dim3(128), 256, 0, stream>>>(w_sk, WTSK);
  wre3<<<dim3(512), 256, 0, stream>>>(w_sv, WTSV);
  wre3<<<dim3(128), 256, 0, stream>>>(w_qq, WTQQK);
  wre3<<<dim3(128), 256, 0, stream>>>(w_qk, WTQQK + (long)128 * 9216);
  cvt_lin<<<dim3(512), 256, 0, stream>>>(w_cq, WCQ, 524288);

  // convs (implicit GEMM)
  gemm_nt<1, 0><<<dim3(240, 1, 1), 256, 0, stream>>>(
      WTSK, 0, 9216, PS, 0, 0, 9216, 1.0f, b_sk, nullptr, SKR, nullptr, 0, 128);
  gemm_nt<1, 1><<<dim3(120, 4, 2), 256, 0, stream>>>(
      WTSV, 0, 9216, PS, 17756160L, 0, 9216, 1.0f, b_sv, nullptr, SVA, nullptr,
      7864320L, 15360);
  gemm_nt<1, 0><<<dim3(80, 2, 1), 256, 0, stream>>>(
      WTQQK, 0, 9216, PQ, 0, 0, 9216, 1.0f, b_qq, b_qk, QQR, QKR, 0, 128);
  gemm_nt<2, 2><<<dim3(80, 4, 1), 256, 0, stream>>>(
      WCQ, 0, 1024, PQ, 0, 0, 1024, 1.0f, b_cq, nullptr, out, nullptr, 0, 0);

  // stage 1: P1^T = (Qmid rows)·(K rows)^T, softmax rows, newV = SV·P1T^T
  gemm_nt<0, 1><<<dim3(120, 8, 2), 256, 0, stream>>>(
      QQR + 262144, 655360L, 128, SKR, 1966080L, 128, 128, SCALE, nullptr,
      nullptr, P1T, nullptr, 15728640L, 15360);
  row_softmax<<<dim3(2048), 256, 0, stream>>>(P1T, 15360);
  gemm_nt<0, 1><<<dim3(8, 4, 2), 256, 0, stream>>>(
      SVA, 7864320L, 15360, P1T, 15728640L, 15360, 15360, 1.0f, nullptr,
      nullptr, NEWV, nullptr, 524288L, 1024);

  // stage 2: P2^T = (QQ rows)·(Kmid rows)^T, softmax rows, Out = newV·P2T^T
  gemm_nt<0, 1><<<dim3(8, 40, 2), 256, 0, stream>>>(
      QQR, 655360L, 128, QKR + 262144, 655360L, 128, 128, SCALE, nullptr,
      nullptr, P2T, nullptr, 5242880L, 1024);
  row_softmax<<<dim3(10240), 256, 0, stream>>>(P2T, 1024);
  gemm_nt<0, 3><<<dim3(40, 4, 2), 256, 0, stream>>>(
      NEWV, 524288L, 1024, P2T, 5242880L, 1024, 1024, 1.0f, nullptr, nullptr,
      out, nullptr, 0, 0);
}

// Round 2
// 838.737 us; speedup vs baseline: 1.1562x; 1.1562x over previous
//
#include <hip/hip_runtime.h>
#include <cstdint>

typedef unsigned short u16;
typedef __attribute__((ext_vector_type(8))) u16 u16x8;
typedef __attribute__((ext_vector_type(4))) u16 u16x4;
typedef __attribute__((ext_vector_type(8))) _Float16 f16x8;
typedef __attribute__((ext_vector_type(4))) float f32x4;

// ---------- helpers ----------
__device__ __forceinline__ u16 f2h(float f) {   // fp32 -> fp16 (RNE)
  _Float16 h = (_Float16)f;
  return __builtin_bit_cast(u16, h);
}
__device__ __forceinline__ float h2f(u16 b) {
  _Float16 h = __builtin_bit_cast(_Float16, b);
  return (float)h;
}
// async global->LDS, 16B per lane. LDS dest = wave-uniform base + lane*16.
__device__ __forceinline__ void gll16(const void* g, void* l) {
  auto gp = reinterpret_cast<const __attribute__((address_space(1))) unsigned int*>(
      reinterpret_cast<uintptr_t>(g));
  auto lp = reinterpret_cast<__attribute__((address_space(3))) unsigned int*>(
      reinterpret_cast<uintptr_t>(l));
  __builtin_amdgcn_global_load_lds(gp, lp, 16, 0, 0);
}

// ---------- prep: zero only the 34x34 halo ----------
__global__ __launch_bounds__(256) void halo_zero(u16* __restrict__ buf) {
  const int img = blockIdx.x, q = blockIdx.y, tid = threadIdx.x;
  u16* base = buf + (long)img * 34 * 34 * 1024;
  u16x8 z8 = {0, 0, 0, 0, 0, 0, 0, 0};
  if (q < 2) {                     // full rows y=0 / y=33 : 34*1024 elems
    u16* r0 = base + (long)(q ? 33 : 0) * 34 * 1024;
    for (int i = tid * 8; i < 34816; i += 2048) *(u16x8*)&r0[i] = z8;
  } else {                         // cols x=0 / x=33, y=1..32
    const int x = (q == 2) ? 0 : 33;
    for (int i = tid * 8; i < 32768; i += 2048) {
      const int y = 1 + (i >> 10), c = i & 1023;
      *(u16x8*)&base[((long)y * 34 + x) * 1024 + c] = z8;
    }
  }
}

// ---------- prep: NCHW fp32 -> padded(34x34) NHWC fp16 ----------
__global__ __launch_bounds__(256) void pad_nhwc(const float* __restrict__ in,
                                                u16* __restrict__ outp) {
  const int img = blockIdx.x >> 5;
  const int y   = blockIdx.x & 31;
  __shared__ float tile[32][33];
  const int tid = threadIdx.x;
  const int xi = tid & 31, ci = tid >> 5;
  const int xo = tid >> 3, q = tid & 7;
  const float* ip = in + (long)img * 1048576 + y * 32;
  u16* op = outp + ((long)(img * 34) + y + 1) * 34 * 1024 + 1024;
  for (int c0 = 0; c0 < 1024; c0 += 32) {
#pragma unroll
    for (int k2 = 0; k2 < 4; k2++)
      tile[k2 * 8 + ci][xi] = ip[(long)(c0 + k2 * 8 + ci) * 1024 + xi];
    __syncthreads();
    u16x4 o4;
#pragma unroll
    for (int r = 0; r < 4; r++) o4[r] = f2h(tile[q * 4 + r][xo]);
    *(u16x4*)&op[(long)xo * 1024 + c0 + q * 4] = o4;
    __syncthreads();
  }
}

// ---------- prep: w[OC][1024][3][3] fp32 -> wT[OC][t*1024+c] fp16 ----------
__global__ __launch_bounds__(256) void wre3(const float* __restrict__ w,
                                            u16* __restrict__ o) {
  const int oc = blockIdx.x;
  __shared__ float buf[9216];
  const float* wp = w + (long)oc * 9216;
  for (int i = threadIdx.x; i < 9216; i += 256) buf[i] = wp[i];
  __syncthreads();
  u16* op = o + (long)oc * 9216;
  for (int k = threadIdx.x; k < 9216; k += 256) {
    int t = k >> 10, c = k & 1023;
    op[k] = f2h(buf[c * 9 + t]);
  }
}

__global__ __launch_bounds__(256) void cvt_lin(const float* __restrict__ in,
                                               u16* __restrict__ o, int n) {
  int i = (blockIdx.x * 256 + threadIdx.x) * 4;
  if (i + 3 < n) {
#pragma unroll
    for (int r = 0; r < 4; r++) o[i + r] = f2h(in[i + r]);
  }
}

// ---------- row softmax (in-place, fp16), 2-pass online ----------
__global__ __launch_bounds__(256) void row_softmax(u16* __restrict__ P, int L) {
  u16* p = P + (long)blockIdx.x * L;
  const int tid = threadIdx.x;
  const int nv = L >> 3;
  __shared__ float rm[4], rs[4];
  float m = -3.0e38f, s = 0.f;
  for (int i = tid; i < nv; i += 256) {
    u16x8 v = *(const u16x8*)(p + (i << 3));
#pragma unroll
    for (int j = 0; j < 8; j++) {
      float x = h2f(v[j]);
      float nm = fmaxf(m, x);
      s = s * __expf(m - nm) + __expf(x - nm);
      m = nm;
    }
  }
#pragma unroll
  for (int o = 32; o > 0; o >>= 1) {
    float om = __shfl_xor(m, o, 64), os = __shfl_xor(s, o, 64);
    float nm = fmaxf(m, om);
    s = s * __expf(m - nm) + os * __expf(om - nm);
    m = nm;
  }
  if ((tid & 63) == 0) { rm[tid >> 6] = m; rs[tid >> 6] = s; }
  __syncthreads();
  float M = rm[0], S = rs[0];
#pragma unroll
  for (int w = 1; w < 4; w++) {
    float nm = fmaxf(M, rm[w]);
    S = S * __expf(M - nm) + rs[w] * __expf(rm[w] - nm);
    M = nm;
  }
  const float inv = 1.0f / S;
  for (int i = tid; i < nv; i += 256) {
    u16x8 v = *(const u16x8*)(p + (i << 3));
    u16x8 o8;
#pragma unroll
    for (int j = 0; j < 8; j++) o8[j] = f2h(__expf(h2f(v[j]) - M) * inv);
    *(u16x8*)(p + (i << 3)) = o8;
  }
}

// ---------- split-K partial reduce: NEWV fp16 = sum_c PART[b*4+c] ----------
__global__ __launch_bounds__(256) void reduce4(const float* __restrict__ part,
                                               u16* __restrict__ o) {
  long j = ((long)blockIdx.x * 256 + threadIdx.x) * 4;
  int b = (int)(j >> 19);
  long i = j & 524287;
  const float* p = part + (long)b * 2097152 + i;
  f32x4 s = *(const f32x4*)&p[0];
#pragma unroll
  for (int c = 1; c < 4; c++) {
    f32x4 t = *(const f32x4*)&p[(long)c * 524288];
    s = s + t;
  }
  u16x4 o4;
#pragma unroll
  for (int r = 0; r < 4; r++) o4[r] = f2h(s[r]);
  *(u16x4*)&o[j] = o4;
}

// ---------- 128x128 NT GEMM (2-phase, general purpose) ----------
// BMODE: 0 plain rows [n][K]; 1 = 3x3 conv patches (padded NHWC); 2 = 1x1 center
// EPI: 0 f16 transposed store (dual out); 1 f16 row store *scale(+bias);
//      2 qf fp32 d_out[img][512+m][p]; 3 final fp32 d_out[z*5+f][m][p];
//      4 fp32 partial row store (split-K)
template <int BMODE, int EPI, int SPLITK>
__global__ __launch_bounds__(256, 2)
void gemm_nt(const u16* __restrict__ A, long Azoff, int Astride,
             const u16* __restrict__ B, long Bzoff, int Bstride,
             int K, float scale,
             const float* __restrict__ bias, const float* __restrict__ bias2,
             void* __restrict__ out0, void* __restrict__ out1,
             long out_zoff, int ldo) {
  __shared__ u16 lds[4 * 8192];
  const int tid = threadIdx.x;
  const int lane = tid & 63;
  const int wave = tid >> 6;
  const int mtile = blockIdx.y, ntile = blockIdx.x, z = blockIdx.z;

  const int zb = (SPLITK > 1) ? z / SPLITK : z;
  const int zc = (SPLITK > 1) ? z % SPLITK : 0;
  const u16* Ab = A + (long)zb * Azoff + (long)zc * K;
  const u16* Bb = B + (long)zb * Bzoff + (long)zc * K;

  const int r8 = lane >> 3;
  const int sphys = lane & 7;
  const u16* aSrc[4];
  const u16* bSrc[4];
  u16* aDst[4];
  u16* bDst[4];
#pragma unroll
  for (int i = 0; i < 4; i++) {
    const int row = wave * 32 + i * 8 + r8;
    const int slog = sphys ^ (row & 7);
    aSrc[i] = Ab + (long)(mtile * 128 + row) * Astride + slog * 8;
    if (BMODE == 0) {
      bSrc[i] = Bb + (long)(ntile * 128 + row) * Bstride + slog * 8;
    } else {
      const int n = ntile * 128 + row;
      const int img = n >> 10;
      const int p = n & 1023;
      const int y = p >> 5, x = p & 31;
      bSrc[i] = Bb + ((long)(img * 34 + y) * 34 + x) * 1024 + slog * 8;
    }
    aDst[i] = &lds[0] + (wave * 32 + i * 8) * 64;
    bDst[i] = &lds[0] + 8192 + (wave * 32 + i * 8) * 64;
  }

  const int g = lane >> 4, l15 = lane & 15;
  const int wm = wave >> 1, wn = wave & 1;
  int offA[2][4], offB[2][4];
#pragma unroll
  for (int ks = 0; ks < 2; ks++) {
    const int sl = ks * 4 + g;
#pragma unroll
    for (int i = 0; i < 4; i++) {
      const int ra = wm * 64 + i * 16 + l15;
      offA[ks][i] = ra * 64 + ((sl ^ (ra & 7)) * 8);
      const int rb = wn * 64 + i * 16 + l15;
      offB[ks][i] = 8192 + rb * 64 + ((sl ^ (rb & 7)) * 8);
    }
  }

  auto stage = [&](int buf, int kb) {
    int bAdd;
    if (BMODE == 0) {
      bAdd = kb;
    } else if (BMODE == 1) {
      const int t = kb >> 10, c0 = kb & 1023;
      const int dy = t / 3, dx = t - dy * 3;
      bAdd = (dy * 34 + dx) * 1024 + c0;
    } else {
      bAdd = 35 * 1024 + kb;
    }
    const int bufo = buf * 16384;
#pragma unroll
    for (int i = 0; i < 4; i++) gll16(aSrc[i] + kb, aDst[i] + bufo);
#pragma unroll
    for (int i = 0; i < 4; i++) gll16(bSrc[i] + bAdd, bDst[i] + bufo);
  };

  f32x4 acc[4][4];
  const f32x4 zero = {0.f, 0.f, 0.f, 0.f};
#pragma unroll
  for (int i = 0; i < 4; i++)
#pragma unroll
    for (int j = 0; j < 4; j++) acc[i][j] = zero;

  const int nkt = K >> 6;
  stage(0, 0);
  __syncthreads();
  for (int kt = 0; kt < nkt; ++kt) {
    const int buf = kt & 1;
    if (kt + 1 < nkt) stage(buf ^ 1, (kt + 1) << 6);
#pragma unroll
    for (int ks = 0; ks < 2; ks++) {
      f16x8 af[4], bfg[4];
#pragma unroll
      for (int i = 0; i < 4; i++)
        af[i] = *(const f16x8*)&lds[buf * 16384 + offA[ks][i]];
#pragma unroll
      for (int i = 0; i < 4; i++)
        bfg[i] = *(const f16x8*)&lds[buf * 16384 + offB[ks][i]];
#pragma unroll
      for (int mi = 0; mi < 4; mi++)
#pragma unroll
        for (int ni = 0; ni < 4; ni++)
          acc[mi][ni] = __builtin_amdgcn_mfma_f32_16x16x32_f16(
              af[mi], bfg[ni], acc[mi][ni], 0, 0, 0);
    }
    __syncthreads();
  }

#pragma unroll
  for (int mi = 0; mi < 4; mi++) {
#pragma unroll
    for (int ni = 0; ni < 4; ni++) {
      f32x4 v = acc[mi][ni];
      const int m0 = mtile * 128 + wm * 64 + mi * 16 + g * 4;
      const int n = ntile * 128 + wn * 64 + ni * 16 + l15;
      if (EPI == 0) {
        u16* ob = (u16*)out0;
        const float* bs = bias;
        int mm = m0;
        if (out1 != nullptr && m0 >= 128) { ob = (u16*)out1; bs = bias2; mm = m0 - 128; }
        u16x4 pk;
#pragma unroll
        for (int r = 0; r < 4; r++) {
          float val = v[r] * scale + (bs ? bs[mm + r] : 0.f);
          pk[r] = f2h(val);
        }
        *(u16x4*)&ob[(long)n * ldo + mm] = pk;
      } else if (EPI == 1) {
        u16* ob = (u16*)out0 + (long)z * out_zoff;
#pragma unroll
        for (int r = 0; r < 4; r++) {
          const int m = m0 + r;
          float val = v[r] * scale + (bias ? bias[m] : 0.f);
          ob[(long)m * ldo + n] = f2h(val);
        }
      } else if (EPI == 2) {
        float* of = (float*)out0;
        const int img = n >> 10, p = n & 1023;
#pragma unroll
        for (int r = 0; r < 4; r++) {
          const int m = m0 + r;
          of[(long)img * 1048576 + (long)(512 + m) * 1024 + p] =
              v[r] + (bias ? bias[m] : 0.f);
        }
      } else if (EPI == 3) {
        float* of = (float*)out0;
        const int f = n >> 10, p = n & 1023;
#pragma unroll
        for (int r = 0; r < 4; r++) {
          const int m = m0 + r;
          of[(long)z * 5242880 + (long)f * 1048576 + (long)m * 1024 + p] = v[r];
        }
      } else {  // EPI == 4: fp32 partial row store
        float* of = (float*)out0 + (long)z * out_zoff;
#pragma unroll
        for (int r = 0; r < 4; r++) {
          of[(long)(m0 + r) * ldo + n] = v[r];
        }
      }
    }
  }
}

// ---------- 256x128 deep-pipelined NT GEMM (3-deep ring, counted vmcnt) ----
// B = 3x3 conv patches from padded NHWC. Out: f16 row store + bias.
__global__ __launch_bounds__(512, 1)
void gemm8(const u16* __restrict__ A, int Astride,
           const u16* __restrict__ B, long Bzoff, int K,
           const float* __restrict__ bias,
           u16* __restrict__ out, long out_zoff, int ldo) {
  __shared__ u16 lds[73728];  // A: 3 x 256x64 (49152), B: 3 x 128x64 (24576)
  const int tid = threadIdx.x;
  const int lane = tid & 63;
  const int wave = tid >> 6;

  // XCD-bijective swizzle over 480 blocks (480 % 8 == 0)
  const int nwg = gridDim.x * gridDim.y * gridDim.z;
  const int cpx = nwg >> 3;
  int wg = blockIdx.x + gridDim.x * (blockIdx.y + gridDim.y * blockIdx.z);
  wg = (wg & 7) * cpx + (wg >> 3);
  const int ntile = wg % gridDim.x;
  const int rest = wg / gridDim.x;
  const int mtile = rest % gridDim.y;
  const int z = rest / gridDim.y;

  // ---- staging setup: per wave 4 A-glls (rows wave*32..+32), 2 B-glls ----
  const u16* aS[4]; u16* aD[4];
  const u16* bS[2]; u16* bD[2];
#pragma unroll
  for (int i = 0; i < 4; i++) {
    const int rA = wave * 32 + i * 8 + (lane >> 3);
    const int sl = (lane & 7) ^ (rA & 7);
    aS[i] = A + (long)(mtile * 256 + rA) * Astride + sl * 8;
    aD[i] = &lds[0] + (wave * 32 + i * 8) * 64;
  }
#pragma unroll
  for (int j = 0; j < 2; j++) {
    const int rB = wave * 16 + j * 8 + (lane >> 3);
    const int sl = (lane & 7) ^ (rB & 7);
    const int n = ntile * 128 + rB;
    const int img = n >> 10, p = n & 1023;
    const int y = p >> 5, x = p & 31;
    bS[j] = B + (long)z * Bzoff + ((long)((img * 34 + y) * 34 + x)) * 1024 + sl * 8;
    bD[j] = &lds[0] + 49152 + (wave * 16 + j * 8) * 64;
  }

  // ---- fragment offsets ----
  const int g = lane >> 4, l15 = lane & 15;
  const int wm = wave >> 1, wn = wave & 1;
  int fA[2][4], fB[2][4];
#pragma unroll
  for (int ks = 0; ks < 2; ks++) {
    const int sl = ks * 4 + g;
#pragma unroll
    for (int i = 0; i < 4; i++) {
      const int ra = wm * 64 + i * 16 + l15;
      fA[ks][i] = ra * 64 + ((sl ^ (ra & 7)) * 8);
      const int rb = wn * 64 + i * 16 + l15;
      fB[ks][i] = rb * 64 + ((sl ^ (rb & 7)) * 8);
    }
  }

  auto conv_badd = [](int kb) {
    const int t = kb >> 10, c0 = kb & 1023;
    const int dy = t / 3, dx = t - dy * 3;
    return (dy * 34 + dx) * 1024 + c0;
  };
  auto stageA = [&](int buf, int kb, int i) { gll16(aS[i] + kb, aD[i] + buf * 16384); };
  auto stageB = [&](int buf, int bAdd, int j) { gll16(bS[j] + bAdd, bD[j] + buf * 8192); };

  f32x4 acc[4][4];
  const f32x4 zero = {0.f, 0.f, 0.f, 0.f};
#pragma unroll
  for (int i = 0; i < 4; i++)
#pragma unroll
    for (int j = 0; j < 4; j++) acc[i][j] = zero;

  const int nkt = K >> 6;
  // prologue: stage kt=0 -> buf0, kt=1 -> buf1; gate buf0; barrier
  {
    int b0 = conv_badd(0), b1 = conv_badd(64);
#pragma unroll
    for (int i = 0; i < 4; i++) stageA(0, 0, i);
#pragma unroll
    for (int j = 0; j < 2; j++) stageB(0, b0, j);
#pragma unroll
    for (int i = 0; i < 4; i++) stageA(1, 64, i);
#pragma unroll
    for (int j = 0; j < 2; j++) stageB(1, b1, j);
    asm volatile("s_waitcnt vmcnt(6)" ::: "memory");
    __builtin_amdgcn_s_barrier();
  }

  for (int kt = 0; kt < nkt; ++kt) {
    const int r = kt % 3, w2 = (kt + 2) % 3;
    const bool st = (kt + 2 < nkt);
    const int kb2 = (kt + 2) << 6;
    const int bAdd = st ? conv_badd(kb2) : 0;
    const int rA16 = r * 16384, rB8 = 49152 + r * 8192;
    // ---- phase 0 (ks=0) ----
    {
      f16x8 af[4], bf[4];
#pragma unroll
      for (int i = 0; i < 4; i++) af[i] = *(const f16x8*)&lds[rA16 + fA[0][i]];
#pragma unroll
      for (int i = 0; i < 4; i++) bf[i] = *(const f16x8*)&lds[rB8 + fB[0][i]];
      if (st) { stageA(w2, kb2, 0); stageA(w2, kb2, 1); stageA(w2, kb2, 2); }
      __builtin_amdgcn_s_barrier();
      __builtin_amdgcn_s_setprio(1);
#pragma unroll
      for (int mi = 0; mi < 4; mi++)
#pragma unroll
        for (int ni = 0; ni < 4; ni++)
          acc[mi][ni] = __builtin_amdgcn_mfma_f32_16x16x32_f16(
              af[mi], bf[ni], acc[mi][ni], 0, 0, 0);
      __builtin_amdgcn_s_setprio(0);
      __builtin_amdgcn_s_barrier();
    }
    // ---- phase 1 (ks=1) ----
    {
      f16x8 af[4], bf[4];
#pragma unroll
      for (int i = 0; i < 4; i++) af[i] = *(const f16x8*)&lds[rA16 + fA[1][i]];
#pragma unroll
      for (int i = 0; i < 4; i++) bf[i] = *(const f16x8*)&lds[rB8 + fB[1][i]];
      if (st) { stageA(w2, kb2, 3); stageB(w2, bAdd, 0); stageB(w2, bAdd, 1); }
      // gate next iteration's buffer (counted, never drains prefetch)
      if (kt + 2 < nkt) {
        asm volatile("s_waitcnt vmcnt(6)" ::: "memory");
      } else if (kt + 1 < nkt) {
        asm volatile("s_waitcnt vmcnt(0)" ::: "memory");
      }
      __builtin_amdgcn_s_barrier();
      __builtin_amdgcn_s_setprio(1);
#pragma unroll
      for (int mi = 0; mi < 4; mi++)
#pragma unroll
        for (int ni = 0; ni < 4; ni++)
          acc[mi][ni] = __builtin_amdgcn_mfma_f32_16x16x32_f16(
              af[mi], bf[ni], acc[mi][ni], 0, 0, 0);
      __builtin_amdgcn_s_setprio(0);
      __builtin_amdgcn_s_barrier();
    }
  }

  // ---- epilogue: f16 row store + bias ----
  u16* ob = out + (long)z * out_zoff;
#pragma unroll
  for (int mi = 0; mi < 4; mi++) {
#pragma unroll
    for (int ni = 0; ni < 4; ni++) {
      f32x4 v = acc[mi][ni];
      const int m0 = mtile * 256 + wm * 64 + mi * 16 + g * 4;
      const int n = ntile * 128 + wn * 64 + ni * 16 + l15;
#pragma unroll
      for (int r = 0; r < 4; r++) {
        const int m = m0 + r;
        ob[(long)m * ldo + n] = f2h(v[r] + bias[m]);
      }
    }
  }
}

// ---------- launch ----------
extern "C" void kernel_launch(void* const* d_in, const int* in_sizes, int n_in,
                              void* d_out, int out_size, void* d_ws, size_t ws_size,
                              hipStream_t stream) {
  (void)in_sizes; (void)n_in; (void)out_size;
  const float* query   = (const float*)d_in[0];
  const float* support = (const float*)d_in[1];
  const float* w_sk = (const float*)d_in[2];  const float* b_sk = (const float*)d_in[3];
  const float* w_sv = (const float*)d_in[4];  const float* b_sv = (const float*)d_in[5];
  const float* w_qq = (const float*)d_in[6];  const float* b_qq = (const float*)d_in[7];
  const float* w_qk = (const float*)d_in[8];  const float* b_qk = (const float*)d_in[9];
  const float* w_cq = (const float*)d_in[10]; const float* b_cq = (const float*)d_in[11];
  float* out = (float*)d_out;
  char* ws = (char*)d_ws;

  if (ws_size < 158924800u) return;  // insufficient workspace

  u16* PQ    = (u16*)(ws + 0);           // padded query NHWC f16: 10*34*34*1024
  u16* PS    = (u16*)(ws + 23674880);    // padded support: 30*34*34*1024
  u16* WTSK  = (u16*)(ws + 94699520);    // [128][9216]
  u16* WTSV  = (u16*)(ws + 97058816);    // [512][9216]
  u16* WTQQK = (u16*)(ws + 106496000);   // [256][9216]
  u16* WCQ   = (u16*)(ws + 111214592);   // [512][1024]
  u16* SKR   = (u16*)(ws + 112263168);   // [30720][128]
  u16* SVA   = (u16*)(ws + 120127488);   // [2][512][15360]
  u16* QQR   = (u16*)(ws + 151584768);   // [10240][128]
  u16* QKR   = (u16*)(ws + 154206208);   // [10240][128]
  u16* NEWV  = (u16*)(ws + 156827648);   // [2][512][1024]
  u16* P1T   = PS;                       // alias after sk/sv convs consume PS
  u16* P2T   = PQ;                       // alias after qqk/qf convs consume PQ
  float* PART = (float*)(ws + 94699520); // alias over weights: [8][512][1024] fp32

  const float SCALE = 0.08838834764831843f;  // 1/sqrt(128)

  halo_zero<<<dim3(10, 4), 256, 0, stream>>>(PQ);
  halo_zero<<<dim3(30, 4), 256, 0, stream>>>(PS);
  pad_nhwc<<<dim3(320), 256, 0, stream>>>(query, PQ);
  pad_nhwc<<<dim3(960), 256, 0, stream>>>(support, PS);
  wre3<<<dim3(128), 256, 0, stream>>>(w_sk, WTSK);
  wre3<<<dim3(512), 256, 0, stream>>>(w_sv, WTSV);
  wre3<<<dim3(128), 256, 0, stream>>>(w_qq, WTQQK);
  wre3<<<dim3(128), 256, 0, stream>>>(w_qk, WTQQK + (long)128 * 9216);
  cvt_lin<<<dim3(512), 256, 0, stream>>>(w_cq, WCQ, 524288);

  // convs (implicit GEMM)
  gemm_nt<1, 0, 1><<<dim3(240, 1, 1), 256, 0, stream>>>(
      WTSK, 0, 9216, PS, 0, 0, 9216, 1.0f, b_sk, nullptr, SKR, nullptr, 0, 128);
  gemm8<<<dim3(120, 2, 2), 512, 0, stream>>>(
      WTSV, 9216, PS, 17756160L, 9216, b_sv, SVA, 7864320L, 15360);
  gemm_nt<1, 0, 1><<<dim3(80, 2, 1), 256, 0, stream>>>(
      WTQQK, 0, 9216, PQ, 0, 0, 9216, 1.0f, b_qq, b_qk, QQR, QKR, 0, 128);
  gemm_nt<2, 2, 1><<<dim3(80, 4, 1), 256, 0, stream>>>(
      WCQ, 0, 1024, PQ, 0, 0, 1024, 1.0f, b_cq, nullptr, out, nullptr, 0, 0);

  // stage 1: P1^T = (Qmid rows)·(K rows)^T, softmax rows, newV = SV·P1T^T
  gemm_nt<0, 1, 1><<<dim3(120, 8, 2), 256, 0, stream>>>(
      QQR + 262144, 655360L, 128, SKR, 1966080L, 128, 128, SCALE, nullptr,
      nullptr, P1T, nullptr, 15728640L, 15360);
  row_softmax<<<dim3(2048), 256, 0, stream>>>(P1T, 15360);
  gemm_nt<0, 4, 4><<<dim3(8, 4, 8), 256, 0, stream>>>(
      SVA, 7864320L, 15360, P1T, 15728640L, 15360, 3840, 1.0f, nullptr,
      nullptr, PART, nullptr, 524288L, 1024);
  reduce4<<<dim3(1024), 256, 0, stream>>>(PART, NEWV);

  // stage 2: P2^T = (QQ rows)·(Kmid rows)^T, softmax rows, Out = newV·P2T^T
  gemm_nt<0, 1, 1><<<dim3(8, 40, 2), 256, 0, stream>>>(
      QQR, 655360L, 128, QKR + 262144, 655360L, 128, 128, SCALE, nullptr,
      nullptr, P2T, nullptr, 5242880L, 1024);
  row_softmax<<<dim3(10240), 256, 0, stream>>>(P2T, 1024);
  gemm_nt<0, 3, 1><<<dim3(40, 4, 2), 256, 0, stream>>>(
      NEWV, 524288L, 1024, P2T, 5242880L, 1024, 1024, 1.0f, nullptr, nullptr,
      out, nullptr, 0, 0);
}

// Round 3
// 790.342 us; speedup vs baseline: 1.2270x; 1.0612x over previous
//
#include <hip/hip_runtime.h>
#include <cstdint>

typedef unsigned short u16;
typedef __attribute__((ext_vector_type(8))) u16 u16x8;
typedef __attribute__((ext_vector_type(4))) u16 u16x4;
typedef __attribute__((ext_vector_type(8))) _Float16 f16x8;
typedef __attribute__((ext_vector_type(4))) float f32x4;

// ---------- helpers ----------
__device__ __forceinline__ u16 f2h(float f) {
  _Float16 h = (_Float16)f;
  return __builtin_bit_cast(u16, h);
}
__device__ __forceinline__ float h2f(u16 b) {
  _Float16 h = __builtin_bit_cast(_Float16, b);
  return (float)h;
}
__device__ __forceinline__ void gll16(const void* g, void* l) {
  auto gp = reinterpret_cast<const __attribute__((address_space(1))) unsigned int*>(
      reinterpret_cast<uintptr_t>(g));
  auto lp = reinterpret_cast<__attribute__((address_space(3))) unsigned int*>(
      reinterpret_cast<uintptr_t>(l));
  __builtin_amdgcn_global_load_lds(gp, lp, 16, 0, 0);
}

// ---------- prep: zero only the 34x34 halo ----------
__global__ __launch_bounds__(256) void halo_zero(u16* __restrict__ buf) {
  const int img = blockIdx.x, q = blockIdx.y, tid = threadIdx.x;
  u16* base = buf + (long)img * 34 * 34 * 1024;
  u16x8 z8 = {0, 0, 0, 0, 0, 0, 0, 0};
  if (q < 2) {
    u16* r0 = base + (long)(q ? 33 : 0) * 34 * 1024;
    for (int i = tid * 8; i < 34816; i += 2048) *(u16x8*)&r0[i] = z8;
  } else {
    const int x = (q == 2) ? 0 : 33;
    for (int i = tid * 8; i < 32768; i += 2048) {
      const int y = 1 + (i >> 10), c = i & 1023;
      *(u16x8*)&base[((long)y * 34 + x) * 1024 + c] = z8;
    }
  }
}

// ---------- prep: NCHW fp32 -> padded(34x34) NHWC fp16 ----------
__global__ __launch_bounds__(256) void pad_nhwc(const float* __restrict__ in,
                                                u16* __restrict__ outp) {
  const int img = blockIdx.x >> 5;
  const int y   = blockIdx.x & 31;
  __shared__ float tile[32][33];
  const int tid = threadIdx.x;
  const int xi = tid & 31, ci = tid >> 5;
  const int xo = tid >> 3, q = tid & 7;
  const float* ip = in + (long)img * 1048576 + y * 32;
  u16* op = outp + ((long)(img * 34) + y + 1) * 34 * 1024 + 1024;
  for (int c0 = 0; c0 < 1024; c0 += 32) {
#pragma unroll
    for (int k2 = 0; k2 < 4; k2++)
      tile[k2 * 8 + ci][xi] = ip[(long)(c0 + k2 * 8 + ci) * 1024 + xi];
    __syncthreads();
    u16x4 o4;
#pragma unroll
    for (int r = 0; r < 4; r++) o4[r] = f2h(tile[q * 4 + r][xo]);
    *(u16x4*)&op[(long)xo * 1024 + c0 + q * 4] = o4;
    __syncthreads();
  }
}

// ---------- prep: w[OC][1024][3][3] fp32 -> wT[OC][t*1024+c] fp16 ----------
__global__ __launch_bounds__(256) void wre3(const float* __restrict__ w,
                                            u16* __restrict__ o) {
  const int oc = blockIdx.x;
  __shared__ float buf[9216];
  const float* wp = w + (long)oc * 9216;
  for (int i = threadIdx.x; i < 9216; i += 256) buf[i] = wp[i];
  __syncthreads();
  u16* op = o + (long)oc * 9216;
  for (int k = threadIdx.x; k < 9216; k += 256) {
    int t = k >> 10, c = k & 1023;
    op[k] = f2h(buf[c * 9 + t]);
  }
}

__global__ __launch_bounds__(256) void cvt_lin(const float* __restrict__ in,
                                               u16* __restrict__ o, int n) {
  int i = (blockIdx.x * 256 + threadIdx.x) * 4;
  if (i + 3 < n) {
#pragma unroll
    for (int r = 0; r < 4; r++) o[i + r] = f2h(in[i + r]);
  }
}

// ---------- one-pass register softmax, L=15360 (60 elems/thread) ----------
__global__ __launch_bounds__(256) void row_softmax60(u16* __restrict__ P) {
  u16* p = P + (long)blockIdx.x * 15360;
  const int tid = threadIdx.x;
  __shared__ float rm[4], rs[4];
  u16x4 v[15];
#pragma unroll
  for (int j = 0; j < 15; j++)
    v[j] = *(const u16x4*)(p + ((tid + (j << 8)) << 2));
  float m = -3.0e38f;
#pragma unroll
  for (int j = 0; j < 15; j++)
#pragma unroll
    for (int e = 0; e < 4; e++) m = fmaxf(m, h2f(v[j][e]));
#pragma unroll
  for (int o = 32; o > 0; o >>= 1) m = fmaxf(m, __shfl_xor(m, o, 64));
  if ((tid & 63) == 0) rm[tid >> 6] = m;
  __syncthreads();
  const float M = fmaxf(fmaxf(rm[0], rm[1]), fmaxf(rm[2], rm[3]));
  float s = 0.f;
#pragma unroll
  for (int j = 0; j < 15; j++)
#pragma unroll
    for (int e = 0; e < 4; e++) s += __expf(h2f(v[j][e]) - M);
#pragma unroll
  for (int o = 32; o > 0; o >>= 1) s += __shfl_xor(s, o, 64);
  if ((tid & 63) == 0) rs[tid >> 6] = s;
  __syncthreads();
  const float inv = 1.0f / (rs[0] + rs[1] + rs[2] + rs[3]);
#pragma unroll
  for (int j = 0; j < 15; j++) {
    u16x4 o4;
#pragma unroll
    for (int e = 0; e < 4; e++) o4[e] = f2h(__expf(h2f(v[j][e]) - M) * inv);
    *(u16x4*)(p + ((tid + (j << 8)) << 2)) = o4;
  }
}

// ---------- one-pass register softmax, L=1024 (4 elems/thread) ----------
__global__ __launch_bounds__(256) void row_softmax4(u16* __restrict__ P) {
  u16* p = P + (long)blockIdx.x * 1024;
  const int tid = threadIdx.x;
  __shared__ float rm[4], rs[4];
  u16x4 v = *(const u16x4*)(p + (tid << 2));
  float m = fmaxf(fmaxf(h2f(v[0]), h2f(v[1])), fmaxf(h2f(v[2]), h2f(v[3])));
#pragma unroll
  for (int o = 32; o > 0; o >>= 1) m = fmaxf(m, __shfl_xor(m, o, 64));
  if ((tid & 63) == 0) rm[tid >> 6] = m;
  __syncthreads();
  const float M = fmaxf(fmaxf(rm[0], rm[1]), fmaxf(rm[2], rm[3]));
  float s = 0.f;
#pragma unroll
  for (int e = 0; e < 4; e++) s += __expf(h2f(v[e]) - M);
#pragma unroll
  for (int o = 32; o > 0; o >>= 1) s += __shfl_xor(s, o, 64);
  if ((tid & 63) == 0) rs[tid >> 6] = s;
  __syncthreads();
  const float inv = 1.0f / (rs[0] + rs[1] + rs[2] + rs[3]);
  u16x4 o4;
#pragma unroll
  for (int e = 0; e < 4; e++) o4[e] = f2h(__expf(h2f(v[e]) - M) * inv);
  *(u16x4*)(p + (tid << 2)) = o4;
}

// ---------- split-K partial reduce ----------
__global__ __launch_bounds__(256) void reduce4(const float* __restrict__ part,
                                               u16* __restrict__ o) {
  long j = ((long)blockIdx.x * 256 + threadIdx.x) * 4;
  int b = (int)(j >> 19);
  long i = j & 524287;
  const float* p = part + (long)b * 2097152 + i;
  f32x4 s = *(const f32x4*)&p[0];
#pragma unroll
  for (int c = 1; c < 4; c++) {
    f32x4 t = *(const f32x4*)&p[(long)c * 524288];
    s = s + t;
  }
  u16x4 o4;
#pragma unroll
  for (int r = 0; r < 4; r++) o4[r] = f2h(s[r]);
  *(u16x4*)&o[j] = o4;
}

// ---------- 256x256 4-phase deep GEMM for the sv conv ----------
// A = WTSV [512][9216], B = 3x3 patches from PS, out = SVA [2][512][15360]
__global__ __launch_bounds__(512, 1)
void gemm256(const u16* __restrict__ A, const u16* __restrict__ B,
             const float* __restrict__ bias, u16* __restrict__ out) {
  __shared__ u16 lds[65536];  // 2 buf x (A 256x64 | B 256x64) = 128 KB
  const int tid = threadIdx.x, lane = tid & 63, wave = tid >> 6;
  const int nwg = gridDim.x * gridDim.y;
  int wg = blockIdx.x + gridDim.x * blockIdx.y;
  wg = (wg & 7) * (nwg >> 3) + (wg >> 3);
  const int ntile = wg % gridDim.x;
  const int mtile = wg / gridDim.x;

  // ---- staging: per wave 4 A-glls + 4 B-glls (8 rows x 64k each) ----
  const int slog = (lane & 7) ^ ((lane >> 3) & 7);  // r&7 == (lane>>3)&7
  const u16* aS[4];
  const u16* bS[4];
  int aD[4], bD[4];
#pragma unroll
  for (int j = 0; j < 4; j++) {
    const int r = wave * 32 + j * 8 + (lane >> 3);
    aS[j] = A + (long)(mtile * 256 + r) * 9216 + slog * 8;
    aD[j] = (wave * 32 + j * 8) * 64;
    const int n = ntile * 256 + r;
    const int img = n >> 10, p = n & 1023;
    const int y = p >> 5, x = p & 31;
    bS[j] = B + ((long)((img * 34 + y) * 34 + x)) * 1024 + slog * 8;
    bD[j] = 16384 + (wave * 32 + j * 8) * 64;
  }

  // ---- fragment offsets: ra&7 == l15&7 -> off = rowoff + sx[ks] ----
  const int g = lane >> 4, l15 = lane & 15;
  const int wm = wave >> 2, wn = wave & 3;
  int aRow[8], bRow[4], sx[2];
#pragma unroll
  for (int mi = 0; mi < 8; mi++) aRow[mi] = (wm * 128 + mi * 16 + l15) * 64;
#pragma unroll
  for (int ni = 0; ni < 4; ni++) bRow[ni] = 16384 + (wn * 64 + ni * 16 + l15) * 64;
#pragma unroll
  for (int ks = 0; ks < 2; ks++) sx[ks] = ((ks * 4 + g) ^ (l15 & 7)) * 8;

  f32x4 acc[8][4];
  const f32x4 zero = {0.f, 0.f, 0.f, 0.f};
#pragma unroll
  for (int i = 0; i < 8; i++)
#pragma unroll
    for (int j = 0; j < 4; j++) acc[i][j] = zero;

  const int nkt = 144;  // K = 9216
  // prologue: stage kt=0 -> buf0
  {
#pragma unroll
    for (int j = 0; j < 4; j++) gll16(aS[j], &lds[aD[j]]);
#pragma unroll
    for (int j = 0; j < 4; j++) gll16(bS[j], &lds[bD[j]]);
    asm volatile("s_waitcnt vmcnt(0)" ::: "memory");
    __builtin_amdgcn_s_barrier();
  }

  for (int kt = 0; kt < nkt; ++kt) {
    const int buf = (kt & 1) << 15;
    const int nbuf = buf ^ 32768;
    const bool st = (kt + 1 < nkt);
    const int kb1 = (kt + 1) << 6;
    int bAdd = 0;
    if (st) {
      const int t = kb1 >> 10, c0 = kb1 & 1023;
      const int dy = t / 3, dx = t - dy * 3;
      bAdd = (dy * 34 + dx) * 1024 + c0;
    }
    f16x8 afr[4], bfr[4];
    // ---- phase 0: ks=0, mi 0..3 (load B ks0, held through phase 1) ----
#pragma unroll
    for (int mi = 0; mi < 4; mi++) afr[mi] = *(const f16x8*)&lds[buf + aRow[mi] + sx[0]];
#pragma unroll
    for (int ni = 0; ni < 4; ni++) bfr[ni] = *(const f16x8*)&lds[buf + bRow[ni] + sx[0]];
    if (st) {
      gll16(aS[0] + kb1, &lds[nbuf + aD[0]]);
      gll16(aS[1] + kb1, &lds[nbuf + aD[1]]);
      gll16(bS[0] + bAdd, &lds[nbuf + bD[0]]);
      gll16(bS[1] + bAdd, &lds[nbuf + bD[1]]);
    }
    __builtin_amdgcn_s_barrier();
    __builtin_amdgcn_s_setprio(1);
#pragma unroll
    for (int mi = 0; mi < 4; mi++)
#pragma unroll
      for (int ni = 0; ni < 4; ni++)
        acc[mi][ni] = __builtin_amdgcn_mfma_f32_16x16x32_f16(afr[mi], bfr[ni], acc[mi][ni], 0, 0, 0);
    __builtin_amdgcn_s_setprio(0);
    __builtin_amdgcn_s_barrier();
    // ---- phase 1: ks=0, mi 4..7 (reuse bfr) ----
#pragma unroll
    for (int mi = 0; mi < 4; mi++) afr[mi] = *(const f16x8*)&lds[buf + aRow[mi + 4] + sx[0]];
    if (st) {
      gll16(aS[2] + kb1, &lds[nbuf + aD[2]]);
      gll16(aS[3] + kb1, &lds[nbuf + aD[3]]);
      gll16(bS[2] + bAdd, &lds[nbuf + bD[2]]);
      gll16(bS[3] + bAdd, &lds[nbuf + bD[3]]);
    }
    __builtin_amdgcn_s_barrier();
    __builtin_amdgcn_s_setprio(1);
#pragma unroll
    for (int mi = 0; mi < 4; mi++)
#pragma unroll
      for (int ni = 0; ni < 4; ni++)
        acc[mi + 4][ni] = __builtin_amdgcn_mfma_f32_16x16x32_f16(afr[mi], bfr[ni], acc[mi + 4][ni], 0, 0, 0);
    __builtin_amdgcn_s_setprio(0);
    __builtin_amdgcn_s_barrier();
    // ---- phase 2: ks=1, mi 0..3 ----
#pragma unroll
    for (int mi = 0; mi < 4; mi++) afr[mi] = *(const f16x8*)&lds[buf + aRow[mi] + sx[1]];
#pragma unroll
    for (int ni = 0; ni < 4; ni++) bfr[ni] = *(const f16x8*)&lds[buf + bRow[ni] + sx[1]];
    __builtin_amdgcn_s_barrier();
    __builtin_amdgcn_s_setprio(1);
#pragma unroll
    for (int mi = 0; mi < 4; mi++)
#pragma unroll
      for (int ni = 0; ni < 4; ni++)
        acc[mi][ni] = __builtin_amdgcn_mfma_f32_16x16x32_f16(afr[mi], bfr[ni], acc[mi][ni], 0, 0, 0);
    __builtin_amdgcn_s_setprio(0);
    __builtin_amdgcn_s_barrier();
    // ---- phase 3: ks=1, mi 4..7; gate next buffer at the end ----
#pragma unroll
    for (int mi = 0; mi < 4; mi++) afr[mi] = *(const f16x8*)&lds[buf + aRow[mi + 4] + sx[1]];
    __builtin_amdgcn_s_barrier();
    __builtin_amdgcn_s_setprio(1);
#pragma unroll
    for (int mi = 0; mi < 4; mi++)
#pragma unroll
      for (int ni = 0; ni < 4; ni++)
        acc[mi + 4][ni] = __builtin_amdgcn_mfma_f32_16x16x32_f16(afr[mi], bfr[ni], acc[mi + 4][ni], 0, 0, 0);
    __builtin_amdgcn_s_setprio(0);
    asm volatile("s_waitcnt vmcnt(0)" ::: "memory");
    __builtin_amdgcn_s_barrier();
  }

  // ---- epilogue: SVA[b][m][rem] = acc + bias[m] ----
#pragma unroll
  for (int mi = 0; mi < 8; mi++) {
#pragma unroll
    for (int ni = 0; ni < 4; ni++) {
      f32x4 v = acc[mi][ni];
      const int m0 = mtile * 256 + wm * 128 + mi * 16 + g * 4;
      const int n = ntile * 256 + wn * 64 + ni * 16 + l15;
      const int b = (n >= 15360) ? 1 : 0;
      const int rem = n - b * 15360;
#pragma unroll
      for (int r = 0; r < 4; r++) {
        const int m = m0 + r;
        out[(long)b * 7864320 + (long)m * 15360 + rem] = f2h(v[r] + bias[m]);
      }
    }
  }
}

// ---------- 128x128 NT GEMM (2-phase, general purpose) ----------
template <int BMODE, int EPI, int SPLITK>
__global__ __launch_bounds__(256, 2)
void gemm_nt(const u16* __restrict__ A, long Azoff, int Astride,
             const u16* __restrict__ B, long Bzoff, int Bstride,
             int K, float scale,
             const float* __restrict__ bias, const float* __restrict__ bias2,
             void* __restrict__ out0, void* __restrict__ out1,
             long out_zoff, int ldo) {
  __shared__ u16 lds[4 * 8192];
  const int tid = threadIdx.x;
  const int lane = tid & 63;
  const int wave = tid >> 6;
  const int mtile = blockIdx.y, ntile = blockIdx.x, z = blockIdx.z;

  const int zb = (SPLITK > 1) ? z / SPLITK : z;
  const int zc = (SPLITK > 1) ? z % SPLITK : 0;
  const u16* Ab = A + (long)zb * Azoff + (long)zc * K;
  const u16* Bb = B + (long)zb * Bzoff + (long)zc * K;

  const int r8 = lane >> 3;
  const int sphys = lane & 7;
  const u16* aSrc[4];
  const u16* bSrc[4];
  u16* aDst[4];
  u16* bDst[4];
#pragma unroll
  for (int i = 0; i < 4; i++) {
    const int row = wave * 32 + i * 8 + r8;
    const int slog = sphys ^ (row & 7);
    aSrc[i] = Ab + (long)(mtile * 128 + row) * Astride + slog * 8;
    if (BMODE == 0) {
      bSrc[i] = Bb + (long)(ntile * 128 + row) * Bstride + slog * 8;
    } else {
      const int n = ntile * 128 + row;
      const int img = n >> 10;
      const int p = n & 1023;
      const int y = p >> 5, x = p & 31;
      bSrc[i] = Bb + ((long)(img * 34 + y) * 34 + x) * 1024 + slog * 8;
    }
    aDst[i] = &lds[0] + (wave * 32 + i * 8) * 64;
    bDst[i] = &lds[0] + 8192 + (wave * 32 + i * 8) * 64;
  }

  const int g = lane >> 4, l15 = lane & 15;
  const int wm = wave >> 1, wn = wave & 1;
  int offA[2][4], offB[2][4];
#pragma unroll
  for (int ks = 0; ks < 2; ks++) {
    const int sl = ks * 4 + g;
#pragma unroll
    for (int i = 0; i < 4; i++) {
      const int ra = wm * 64 + i * 16 + l15;
      offA[ks][i] = ra * 64 + ((sl ^ (ra & 7)) * 8);
      const int rb = wn * 64 + i * 16 + l15;
      offB[ks][i] = 8192 + rb * 64 + ((sl ^ (rb & 7)) * 8);
    }
  }

  auto stage = [&](int buf, int kb) {
    int bAdd;
    if (BMODE == 0) {
      bAdd = kb;
    } else if (BMODE == 1) {
      const int t = kb >> 10, c0 = kb & 1023;
      const int dy = t / 3, dx = t - dy * 3;
      bAdd = (dy * 34 + dx) * 1024 + c0;
    } else {
      bAdd = 35 * 1024 + kb;
    }
    const int bufo = buf * 16384;
#pragma unroll
    for (int i = 0; i < 4; i++) gll16(aSrc[i] + kb, aDst[i] + bufo);
#pragma unroll
    for (int i = 0; i < 4; i++) gll16(bSrc[i] + bAdd, bDst[i] + bufo);
  };

  f32x4 acc[4][4];
  const f32x4 zero = {0.f, 0.f, 0.f, 0.f};
#pragma unroll
  for (int i = 0; i < 4; i++)
#pragma unroll
    for (int j = 0; j < 4; j++) acc[i][j] = zero;

  const int nkt = K >> 6;
  stage(0, 0);
  __syncthreads();
  for (int kt = 0; kt < nkt; ++kt) {
    const int buf = kt & 1;
    if (kt + 1 < nkt) stage(buf ^ 1, (kt + 1) << 6);
#pragma unroll
    for (int ks = 0; ks < 2; ks++) {
      f16x8 af[4], bfg[4];
#pragma unroll
      for (int i = 0; i < 4; i++)
        af[i] = *(const f16x8*)&lds[buf * 16384 + offA[ks][i]];
#pragma unroll
      for (int i = 0; i < 4; i++)
        bfg[i] = *(const f16x8*)&lds[buf * 16384 + offB[ks][i]];
#pragma unroll
      for (int mi = 0; mi < 4; mi++)
#pragma unroll
        for (int ni = 0; ni < 4; ni++)
          acc[mi][ni] = __builtin_amdgcn_mfma_f32_16x16x32_f16(
              af[mi], bfg[ni], acc[mi][ni], 0, 0, 0);
    }
    __syncthreads();
  }

#pragma unroll
  for (int mi = 0; mi < 4; mi++) {
#pragma unroll
    for (int ni = 0; ni < 4; ni++) {
      f32x4 v = acc[mi][ni];
      const int m0 = mtile * 128 + wm * 64 + mi * 16 + g * 4;
      const int n = ntile * 128 + wn * 64 + ni * 16 + l15;
      if (EPI == 0) {
        u16* ob = (u16*)out0;
        const float* bs = bias;
        int mm = m0;
        if (out1 != nullptr && m0 >= 128) { ob = (u16*)out1; bs = bias2; mm = m0 - 128; }
        u16x4 pk;
#pragma unroll
        for (int r = 0; r < 4; r++) {
          float val = v[r] * scale + (bs ? bs[mm + r] : 0.f);
          pk[r] = f2h(val);
        }
        *(u16x4*)&ob[(long)n * ldo + mm] = pk;
      } else if (EPI == 1) {
        u16* ob = (u16*)out0 + (long)z * out_zoff;
#pragma unroll
        for (int r = 0; r < 4; r++) {
          const int m = m0 + r;
          float val = v[r] * scale + (bias ? bias[m] : 0.f);
          ob[(long)m * ldo + n] = f2h(val);
        }
      } else if (EPI == 2) {
        float* of = (float*)out0;
        const int img = n >> 10, p = n & 1023;
#pragma unroll
        for (int r = 0; r < 4; r++) {
          const int m = m0 + r;
          of[(long)img * 1048576 + (long)(512 + m) * 1024 + p] =
              v[r] + (bias ? bias[m] : 0.f);
        }
      } else if (EPI == 3) {
        float* of = (float*)out0;
        const int f = n >> 10, p = n & 1023;
#pragma unroll
        for (int r = 0; r < 4; r++) {
          const int m = m0 + r;
          of[(long)z * 5242880 + (long)f * 1048576 + (long)m * 1024 + p] = v[r];
        }
      } else {  // EPI == 4: fp32 partial row store (split-K)
        float* of = (float*)out0 + (long)z * out_zoff;
#pragma unroll
        for (int r = 0; r < 4; r++) {
          of[(long)(m0 + r) * ldo + n] = v[r];
        }
      }
    }
  }
}

// ---------- launch ----------
extern "C" void kernel_launch(void* const* d_in, const int* in_sizes, int n_in,
                              void* d_out, int out_size, void* d_ws, size_t ws_size,
                              hipStream_t stream) {
  (void)in_sizes; (void)n_in; (void)out_size;
  const float* query   = (const float*)d_in[0];
  const float* support = (const float*)d_in[1];
  const float* w_sk = (const float*)d_in[2];  const float* b_sk = (const float*)d_in[3];
  const float* w_sv = (const float*)d_in[4];  const float* b_sv = (const float*)d_in[5];
  const float* w_qq = (const float*)d_in[6];  const float* b_qq = (const float*)d_in[7];
  const float* w_qk = (const float*)d_in[8];  const float* b_qk = (const float*)d_in[9];
  const float* w_cq = (const float*)d_in[10]; const float* b_cq = (const float*)d_in[11];
  float* out = (float*)d_out;
  char* ws = (char*)d_ws;

  if (ws_size < 158924800u) return;

  u16* PQ    = (u16*)(ws + 0);           // padded query NHWC f16: 10*34*34*1024
  u16* PS    = (u16*)(ws + 23674880);    // padded support: 30*34*34*1024
  u16* WTSK  = (u16*)(ws + 94699520);    // [128][9216]
  u16* WTSV  = (u16*)(ws + 97058816);    // [512][9216]
  u16* WTQQK = (u16*)(ws + 106496000);   // [256][9216]
  u16* WCQ   = (u16*)(ws + 111214592);   // [512][1024]
  u16* SKR   = (u16*)(ws + 112263168);   // [30720][128]
  u16* SVA   = (u16*)(ws + 120127488);   // [2][512][15360]
  u16* QQR   = (u16*)(ws + 151584768);   // [10240][128]
  u16* QKR   = (u16*)(ws + 154206208);   // [10240][128]
  u16* NEWV  = (u16*)(ws + 156827648);   // [2][512][1024]
  u16* P1T   = PS;                       // alias after sk/sv convs consume PS
  u16* P2T   = PQ;                       // alias after qqk/qf convs consume PQ
  float* PART = (float*)(ws + 94699520); // alias over weights: [8][512][1024] fp32

  const float SCALE = 0.08838834764831843f;  // 1/sqrt(128)

  halo_zero<<<dim3(10, 4), 256, 0, stream>>>(PQ);
  halo_zero<<<dim3(30, 4), 256, 0, stream>>>(PS);
  pad_nhwc<<<dim3(320), 256, 0, stream>>>(query, PQ);
  pad_nhwc<<<dim3(960), 256, 0, stream>>>(support, PS);
  wre3<<<dim3(128), 256, 0, stream>>>(w_sk, WTSK);
  wre3<<<dim3(512), 256, 0, stream>>>(w_sv, WTSV);
  wre3<<<dim3(128), 256, 0, stream>>>(w_qq, WTQQK);
  wre3<<<dim3(128), 256, 0, stream>>>(w_qk, WTQQK + (long)128 * 9216);
  cvt_lin<<<dim3(512), 256, 0, stream>>>(w_cq, WCQ, 524288);

  // convs (implicit GEMM)
  gemm_nt<1, 0, 1><<<dim3(240, 1, 1), 256, 0, stream>>>(
      WTSK, 0, 9216, PS, 0, 0, 9216, 1.0f, b_sk, nullptr, SKR, nullptr, 0, 128);
  gemm256<<<dim3(120, 2), 512, 0, stream>>>(WTSV, PS, b_sv, SVA);
  gemm_nt<1, 0, 1><<<dim3(80, 2, 1), 256, 0, stream>>>(
      WTQQK, 0, 9216, PQ, 0, 0, 9216, 1.0f, b_qq, b_qk, QQR, QKR, 0, 128);
  gemm_nt<2, 2, 1><<<dim3(80, 4, 1), 256, 0, stream>>>(
      WCQ, 0, 1024, PQ, 0, 0, 1024, 1.0f, b_cq, nullptr, out, nullptr, 0, 0);

  // stage 1
  gemm_nt<0, 1, 1><<<dim3(120, 8, 2), 256, 0, stream>>>(
      QQR + 262144, 655360L, 128, SKR, 1966080L, 128, 128, SCALE, nullptr,
      nullptr, P1T, nullptr, 15728640L, 15360);
  row_softmax60<<<dim3(2048), 256, 0, stream>>>(P1T);
  gemm_nt<0, 4, 4><<<dim3(8, 4, 8), 256, 0, stream>>>(
      SVA, 7864320L, 15360, P1T, 15728640L, 15360, 3840, 1.0f, nullptr,
      nullptr, PART, nullptr, 524288L, 1024);
  reduce4<<<dim3(1024), 256, 0, stream>>>(PART, NEWV);

  // stage 2
  gemm_nt<0, 1, 1><<<dim3(8, 40, 2), 256, 0, stream>>>(
      QQR, 655360L, 128, QKR + 262144, 655360L, 128, 128, SCALE, nullptr,
      nullptr, P2T, nullptr, 5242880L, 1024);
  row_softmax4<<<dim3(10240), 256, 0, stream>>>(P2T);
  gemm_nt<0, 3, 1><<<dim3(40, 4, 2), 256, 0, stream>>>(
      NEWV, 524288L, 1024, P2T, 5242880L, 1024, 1024, 1.0f, nullptr, nullptr,
      out, nullptr, 0, 0);
}